// Round 10
// baseline (202.068 us; speedup 1.0000x reference)
//
#include <hip/hip_runtime.h>
#include <hip/hip_bf16.h>

typedef unsigned short u16;
typedef unsigned int u32;
typedef __bf16 bf16x8 __attribute__((ext_vector_type(8)));
typedef float f32x4 __attribute__((ext_vector_type(4)));
typedef unsigned int u32x4 __attribute__((ext_vector_type(4)));
typedef unsigned int u32x2 __attribute__((ext_vector_type(2)));

#define NN 512
#define LL 40
#define DD 128
#define OO 256
#define KK 9
#define MHCL 34
#define TT 32
#define PSTR 136   // pept LDS row stride (u16) -- fallback kernel only
#define KDSTR 72   // kern_s row stride (u16): 64 d + 8 pad
#define WPADL 64   // padded l-dim in preconverted W

#define PEPT_U16 (LL * PSTR)    // fallback only
#define KS_U16   (32 * KDSTR)   // 2304 u16 = 4608 B per-wave kern scratch

__device__ __forceinline__ u16 f2bf(float x) {
    unsigned int u = __builtin_bit_cast(unsigned int, x);
    u = (u + 0x7FFFu + ((u >> 16) & 1u)) >> 16;
    return (u16)u;
}
__device__ __forceinline__ u32 pk2(float a, float b) {
    __hip_bfloat162 h = __float22bfloat162_rn(make_float2(a, b)); // x = low half
    u32 r;
    __builtin_memcpy(&r, &h, 4);
    return r;
}
__device__ __forceinline__ bf16x8 ld8(const u16* p) {   // LDS or global, 16B
    u32x4 r;
    __builtin_memcpy(&r, __builtin_assume_aligned(p, 16), 16);
    return __builtin_bit_cast(bf16x8, r);
}
__device__ __forceinline__ f32x4 mfma16(bf16x8 a, bf16x8 b, f32x4 c) {
    return __builtin_amdgcn_mfma_f32_16x16x32_bf16(a, b, c, 0, 0, 0);
}

// prologue 1: W fp32 [O][K][34] -> bf16 zero-padded [O][K][64] in ws
__global__ void w_convert(const float* __restrict__ wgt, u32* __restrict__ wp) {
    int i = blockIdx.x * 256 + threadIdx.x;        // 36864 u32 outputs
    if (i >= OO * KK * (WPADL / 2)) return;
    int o = i / (KK * (WPADL / 2));
    int r = i - o * (KK * (WPADL / 2));
    int k = r >> 5;
    int lp = (r & 31) << 1;
    const float* src = wgt + ((size_t)o * KK + k) * MHCL;
    float a = (lp     < MHCL) ? src[lp]     : 0.f;
    float b = (lp + 1 < MHCL) ? src[lp + 1] : 0.f;
    wp[i] = pk2(a, b);
}

// prologue 2: pept fp32 [N][L][D] -> bf16 same layout in ws (5.24 MB)
__global__ void p_convert(const float* __restrict__ pept, u32* __restrict__ pp) {
    size_t i = (size_t)blockIdx.x * 256 + threadIdx.x;   // u32 pairs
    if (i >= (size_t)NN * LL * DD / 2) return;
    pp[i] = pk2(pept[2 * i], pept[2 * i + 1]);
}

// R10: delete pept LDS. R9 (54.5us): VALU 42% top pipe, occupancy stuck at
// ~11 waves (LDS 29.7KB -> 5-block cap); bank-"conflict" counter is inherent
// b128 serialization (patterns tile banks perfectly), not a lever. Here pept
// is pre-converted to bf16 in ws (p_convert) and stage2 A-frags load DIRECTLY
// from global (16B, L2-hot: 10KB/sample x 4 blocks). Removes staging loop,
// its barrier (block = zero barriers until epilogue), 10.9KB LDS, staging
// VALU. LDS 18.4KB -> 8 blocks/CU; drift regime (R7/R8) feeds on the TLP.
// launch_bounds(256,6): cap 85 (R1: hard-64 cap spilled; demand ~60-70).
__global__ __launch_bounds__(256, 6)
void iconv_fast(const float* __restrict__ mhc,
                const u16* __restrict__ wp,
                const u16* __restrict__ pb,
                const float* __restrict__ bias,
                float* __restrict__ out)
{
    // LDS 18432 B: 4 x wave-private kern_s[32 o'][72]
    // (kern_s doubles as the pair's acc-exchange buffer in the epilogue).
    __shared__ __align__(16) u16 s_ks[4 * KS_U16];

    const int tid  = threadIdx.x;
    const int wave = tid >> 6;
    const int pair = wave >> 1;     // pair index within block (0,1)
    const int dh   = wave & 1;      // d-half owner: d in [dh*64, dh*64+64)
    const int lane = tid & 63;
    const int quad = lane >> 4;
    const int l16  = lane & 15;

    const int n  = blockIdx.x >> 2;     // 4 blocks per sample
    const int oq = blockIdx.x & 3;      // o-quarter: chunks {oq*2, oq*2+1}
    const int obase = (oq * 2 + pair) * 32;   // this pair's single o-chunk

    u16* const ks = s_ks + wave * KS_U16;   // wave-private

    auto loadW = [&](int o_base, int k, bf16x8 wF[2][2]) {
        #pragma unroll
        for (int mt = 0; mt < 2; ++mt) {
            const u16* wr = wp + ((size_t)(o_base + mt * 16 + l16) * KK + k) * WPADL;
            u32x4 r0, r1;
            __builtin_memcpy(&r0, __builtin_assume_aligned(wr + quad * 8, 16), 16);
            __builtin_memcpy(&r1, __builtin_assume_aligned(wr + 32 + quad * 8, 16), 16);
            wF[mt][0] = __builtin_bit_cast(bf16x8, r0);
            wF[mt][1] = __builtin_bit_cast(bf16x8, r1);
        }
    };

    // first W fragments in flight under the mA build
    bf16x8 wB[2][2];
    loadW(obase, 0, wB);

    // ---- mA fragments DIRECT from global (no LDS, no barrier) ----
    // mA[di][ki] = mhc[l = ki*32 + quad*8 + j][d = dh*64 + di*16 + l16], bf16;
    // l >= MHCL are zero: slice ki=1 has only l=32,33 real (quad==0, j<2).
    bf16x8 mA[4][2];
    {
        const float* mg = mhc + (size_t)n * MHCL * DD;
        #pragma unroll
        for (int di = 0; di < 4; ++di) {
            const int d = dh * 64 + di * 16 + l16;
            u16 h0[8];
            #pragma unroll
            for (int j = 0; j < 8; ++j)
                h0[j] = f2bf(mg[(size_t)(quad * 8 + j) * DD + d]);
            __builtin_memcpy(&mA[di][0], h0, 16);
            u16 h1[8] = {0,0,0,0,0,0,0,0};
            if (quad == 0) {
                h1[0] = f2bf(mg[(size_t)32 * DD + d]);
                h1[1] = f2bf(mg[(size_t)33 * DD + d]);
            }
            __builtin_memcpy(&mA[di][1], h1, 16);
        }
    }

    const u16* const pr = pb + (size_t)n * LL * DD;   // this sample's bf16 pept

    // acc[ti][oj]: out[t = ti*16 + quad*4 + r][o' = oj*16 + l16], partial over this d-half
    f32x4 acc00 = {0.f,0.f,0.f,0.f}, acc01 = acc00, acc10 = acc00, acc11 = acc00;

    // ZERO-barrier drift k-loop: all LDS deps same-wave (private scratch);
    // pept A-frags straight from global bf16 (imm-offset foldable, L2-hot).
    #pragma unroll 3
    for (int k = 0; k < KK; ++k) {
        // stage1: kern[o'=32][d_local=64] for this k -> private scratch
        #pragma unroll
        for (int di = 0; di < 4; ++di) {
            f32x4 c0 = {0.f,0.f,0.f,0.f}, c1 = c0;
            c0 = mfma16(mA[di][0], wB[0][0], c0);   // C[d][o' 0..15]
            c0 = mfma16(mA[di][1], wB[0][1], c0);
            c1 = mfma16(mA[di][0], wB[1][0], c1);   // C[d][o' 16..31]
            c1 = mfma16(mA[di][1], wB[1][1], c1);
            u32x2 p0 = { pk2(fmaxf(c0[0], 0.f), fmaxf(c0[1], 0.f)),
                         pk2(fmaxf(c0[2], 0.f), fmaxf(c0[3], 0.f)) };
            u32x2 p1 = { pk2(fmaxf(c1[0], 0.f), fmaxf(c1[1], 0.f)),
                         pk2(fmaxf(c1[2], 0.f), fmaxf(c1[3], 0.f)) };
            __builtin_memcpy(__builtin_assume_aligned(&ks[l16 * KDSTR + di * 16 + quad * 4], 8), &p0, 8);
            __builtin_memcpy(__builtin_assume_aligned(&ks[(16 + l16) * KDSTR + di * 16 + quad * 4], 8), &p1, 8);
        }
        // refill wB (fully consumed by stage1 above); latency covered by stage2
        if (k < KK - 1) loadW(obase, k + 1, wB);
        // stage2: acc += pept[t][d] * kern[d][o'], kdim = 64 in 2 slices
        #pragma unroll
        for (int ds = 0; ds < 2; ++ds) {
            bf16x8 kb0 = ld8(&ks[l16 * KDSTR + ds * 32 + quad * 8]);
            bf16x8 kb1 = ld8(&ks[(16 + l16) * KDSTR + ds * 32 + quad * 8]);
            bf16x8 ap0 = ld8(&pr[(size_t)(k + l16) * DD + dh * 64 + ds * 32 + quad * 8]);
            bf16x8 ap1 = ld8(&pr[(size_t)(k + 16 + l16) * DD + dh * 64 + ds * 32 + quad * 8]);
            acc00 = mfma16(ap0, kb0, acc00);
            acc01 = mfma16(ap0, kb1, acc01);
            acc10 = mfma16(ap1, kb0, acc10);
            acc11 = mfma16(ap1, kb1, acc11);
        }
    }

    // ---- pair reduction: odd wave parks acc in its own scratch; even sums+stores ----
    if (dh == 1) {
        float* ox = (float*)ks;            // 64 lanes x 16 f32 = 4096 B <= 4608
        const int fb = lane * 16;
        __builtin_memcpy(__builtin_assume_aligned(&ox[fb +  0], 16), &acc00, 16);
        __builtin_memcpy(__builtin_assume_aligned(&ox[fb +  4], 16), &acc01, 16);
        __builtin_memcpy(__builtin_assume_aligned(&ox[fb +  8], 16), &acc10, 16);
        __builtin_memcpy(__builtin_assume_aligned(&ox[fb + 12], 16), &acc11, 16);
    }
    __syncthreads();
    if (dh == 0) {
        const float* px = (const float*)(s_ks + (wave + 1) * KS_U16);
        const int fb = lane * 16;
        f32x4 q00, q01, q10, q11;
        __builtin_memcpy(&q00, __builtin_assume_aligned(&px[fb +  0], 16), 16);
        __builtin_memcpy(&q01, __builtin_assume_aligned(&px[fb +  4], 16), 16);
        __builtin_memcpy(&q10, __builtin_assume_aligned(&px[fb +  8], 16), 16);
        __builtin_memcpy(&q11, __builtin_assume_aligned(&px[fb + 12], 16), 16);
        const float bv0 = bias[obase + l16];
        const float bv1 = bias[obase + 16 + l16];
        f32x4 r00 = acc00 + q00 + bv0;
        f32x4 r01 = acc01 + q01 + bv1;
        f32x4 r10 = acc10 + q10 + bv0;
        f32x4 r11 = acc11 + q11 + bv1;
        float* ob = out + ((size_t)n * OO + obase) * TT;
        __builtin_memcpy(__builtin_assume_aligned(ob + (size_t)l16 * TT + quad * 4, 16), &r00, 16);
        __builtin_memcpy(__builtin_assume_aligned(ob + (size_t)(16 + l16) * TT + quad * 4, 16), &r01, 16);
        __builtin_memcpy(__builtin_assume_aligned(ob + (size_t)l16 * TT + 16 + quad * 4, 16), &r10, 16);
        __builtin_memcpy(__builtin_assume_aligned(ob + (size_t)(16 + l16) * TT + 16 + quad * 4, 16), &r11, 16);
    }
}

// ---------- fallback (ws too small): R9 kernel, fp32 paths, LDS pept ----------
__global__ __launch_bounds__(256, 2)
void iconv_ref(const float* __restrict__ pept,
               const float* __restrict__ mhc,
               const float* __restrict__ wgt,
               const float* __restrict__ bias,
               float* __restrict__ out)
{
    __shared__ __align__(16) u16 s_mem[PEPT_U16 + 4 * KS_U16];
    const int tid  = threadIdx.x;
    const int wave = tid >> 6;
    const int pair = wave >> 1;
    const int dh   = wave & 1;
    const int lane = tid & 63;
    const int quad = lane >> 4;
    const int l16  = lane & 15;
    const int n  = blockIdx.x >> 2;
    const int oq = blockIdx.x & 3;
    const int obase = (oq * 2 + pair) * 32;
    u16* const s_pept = s_mem;
    u16* const ks     = s_mem + PEPT_U16 + wave * KS_U16;

    auto loadW = [&](int o_base, int k, bf16x8 wF[2][2]) {
        #pragma unroll
        for (int mt = 0; mt < 2; ++mt) {
            const float* wrow = wgt + ((size_t)(o_base + mt * 16 + l16) * KK + k) * MHCL;
            float w8[8];
            __builtin_memcpy(w8, __builtin_assume_aligned(wrow + quad * 8, 8), 32);
            u16 h0[8];
            #pragma unroll
            for (int j = 0; j < 8; ++j) h0[j] = f2bf(w8[j]);
            __builtin_memcpy(&wF[mt][0], h0, 16);
            u16 h1[8] = {0,0,0,0,0,0,0,0};
            if (quad == 0) { h1[0] = f2bf(wrow[32]); h1[1] = f2bf(wrow[33]); }
            __builtin_memcpy(&wF[mt][1], h1, 16);
        }
    };

    bf16x8 wB[2][2];
    loadW(obase, 0, wB);

    bf16x8 mA[4][2];
    {
        const float* mg = mhc + (size_t)n * MHCL * DD;
        #pragma unroll
        for (int di = 0; di < 4; ++di) {
            const int d = dh * 64 + di * 16 + l16;
            u16 h0[8];
            #pragma unroll
            for (int j = 0; j < 8; ++j)
                h0[j] = f2bf(mg[(size_t)(quad * 8 + j) * DD + d]);
            __builtin_memcpy(&mA[di][0], h0, 16);
            u16 h1[8] = {0,0,0,0,0,0,0,0};
            if (quad == 0) {
                h1[0] = f2bf(mg[(size_t)32 * DD + d]);
                h1[1] = f2bf(mg[(size_t)33 * DD + d]);
            }
            __builtin_memcpy(&mA[di][1], h1, 16);
        }
    }

    {
        const float* pg = pept + (size_t)n * LL * DD;
        #pragma unroll 1
        for (int i = tid; i < (LL * DD) / 4; i += 256) {
            int row = i >> 5, c4 = (i & 31) << 2;
            f32x4 v;
            __builtin_memcpy(&v, __builtin_assume_aligned(pg + row * DD + c4, 16), 16);
            u32x2 h = { pk2(v[0], v[1]), pk2(v[2], v[3]) };
            __builtin_memcpy(__builtin_assume_aligned(&s_pept[row * PSTR + c4], 8), &h, 8);
        }
    }
    __syncthreads();

    f32x4 acc00 = {0.f,0.f,0.f,0.f}, acc01 = acc00, acc10 = acc00, acc11 = acc00;

    #pragma unroll 3
    for (int k = 0; k < KK; ++k) {
        #pragma unroll
        for (int di = 0; di < 4; ++di) {
            f32x4 c0 = {0.f,0.f,0.f,0.f}, c1 = c0;
            c0 = mfma16(mA[di][0], wB[0][0], c0);
            c0 = mfma16(mA[di][1], wB[0][1], c0);
            c1 = mfma16(mA[di][0], wB[1][0], c1);
            c1 = mfma16(mA[di][1], wB[1][1], c1);
            u32x2 p0 = { pk2(fmaxf(c0[0], 0.f), fmaxf(c0[1], 0.f)),
                         pk2(fmaxf(c0[2], 0.f), fmaxf(c0[3], 0.f)) };
            u32x2 p1 = { pk2(fmaxf(c1[0], 0.f), fmaxf(c1[1], 0.f)),
                         pk2(fmaxf(c1[2], 0.f), fmaxf(c1[3], 0.f)) };
            __builtin_memcpy(__builtin_assume_aligned(&ks[l16 * KDSTR + di * 16 + quad * 4], 8), &p0, 8);
            __builtin_memcpy(__builtin_assume_aligned(&ks[(16 + l16) * KDSTR + di * 16 + quad * 4], 8), &p1, 8);
        }
        if (k < KK - 1) loadW(obase, k + 1, wB);
        #pragma unroll
        for (int ds = 0; ds < 2; ++ds) {
            bf16x8 kb0 = ld8(&ks[l16 * KDSTR + ds * 32 + quad * 8]);
            bf16x8 kb1 = ld8(&ks[(16 + l16) * KDSTR + ds * 32 + quad * 8]);
            bf16x8 ap0 = ld8(&s_pept[(k + l16) * PSTR + dh * 64 + ds * 32 + quad * 8]);
            bf16x8 ap1 = ld8(&s_pept[(k + 16 + l16) * PSTR + dh * 64 + ds * 32 + quad * 8]);
            acc00 = mfma16(ap0, kb0, acc00);
            acc01 = mfma16(ap0, kb1, acc01);
            acc10 = mfma16(ap1, kb0, acc10);
            acc11 = mfma16(ap1, kb1, acc11);
        }
    }

    if (dh == 1) {
        float* ox = (float*)ks;
        const int fb = lane * 16;
        __builtin_memcpy(__builtin_assume_aligned(&ox[fb +  0], 16), &acc00, 16);
        __builtin_memcpy(__builtin_assume_aligned(&ox[fb +  4], 16), &acc01, 16);
        __builtin_memcpy(__builtin_assume_aligned(&ox[fb +  8], 16), &acc10, 16);
        __builtin_memcpy(__builtin_assume_aligned(&ox[fb + 12], 16), &acc11, 16);
    }
    __syncthreads();
    if (dh == 0) {
        const float* px = (const float*)(s_mem + PEPT_U16 + (wave + 1) * KS_U16);
        const int fb = lane * 16;
        f32x4 q00, q01, q10, q11;
        __builtin_memcpy(&q00, __builtin_assume_aligned(&px[fb +  0], 16), 16);
        __builtin_memcpy(&q01, __builtin_assume_aligned(&px[fb +  4], 16), 16);
        __builtin_memcpy(&q10, __builtin_assume_aligned(&px[fb +  8], 16), 16);
        __builtin_memcpy(&q11, __builtin_assume_aligned(&px[fb + 12], 16), 16);
        const float bv0 = bias[obase + l16];
        const float bv1 = bias[obase + 16 + l16];
        f32x4 r00 = acc00 + q00 + bv0;
        f32x4 r01 = acc01 + q01 + bv1;
        f32x4 r10 = acc10 + q10 + bv0;
        f32x4 r11 = acc11 + q11 + bv1;
        float* ob = out + ((size_t)n * OO + obase) * TT;
        __builtin_memcpy(__builtin_assume_aligned(ob + (size_t)l16 * TT + quad * 4, 16), &r00, 16);
        __builtin_memcpy(__builtin_assume_aligned(ob + (size_t)(16 + l16) * TT + quad * 4, 16), &r01, 16);
        __builtin_memcpy(__builtin_assume_aligned(ob + (size_t)l16 * TT + 16 + quad * 4, 16), &r10, 16);
        __builtin_memcpy(__builtin_assume_aligned(ob + (size_t)(16 + l16) * TT + 16 + quad * 4, 16), &r11, 16);
    }
}

extern "C" void kernel_launch(void* const* d_in, const int* in_sizes, int n_in,
                              void* d_out, int out_size, void* d_ws, size_t ws_size,
                              hipStream_t stream) {
    const float* pept = (const float*)d_in[0];
    const float* mhc  = (const float*)d_in[1];
    const float* wgt  = (const float*)d_in[2];
    const float* bias = (const float*)d_in[3];
    float* out = (float*)d_out;

    const size_t w_bytes = (size_t)OO * KK * WPADL * sizeof(u16);   // 294,912
    const size_t p_bytes = (size_t)NN * LL * DD * sizeof(u16);      // 5,242,880
    if (ws_size >= w_bytes + p_bytes) {
        u16* wp = (u16*)d_ws;
        u16* pp = (u16*)((char*)d_ws + w_bytes);
        w_convert<<<dim3((OO * KK * (WPADL / 2) + 255) / 256), dim3(256), 0, stream>>>(wgt, (u32*)wp);
        p_convert<<<dim3((NN * LL * DD / 2 + 255) / 256), dim3(256), 0, stream>>>(pept, (u32*)pp);
        iconv_fast<<<dim3(NN * 4), dim3(256), 0, stream>>>(mhc, wp, pp, bias, out);
    } else {
        iconv_ref<<<dim3(NN * 4), dim3(256), 0, stream>>>(pept, mhc, wgt, bias, out);
    }
}

// Round 11
// 148.290 us; speedup vs baseline: 1.3626x; 1.3626x over previous
//
#include <hip/hip_runtime.h>
#include <hip/hip_bf16.h>

typedef unsigned short u16;
typedef unsigned int u32;
typedef __bf16 bf16x8 __attribute__((ext_vector_type(8)));
typedef float f32x4 __attribute__((ext_vector_type(4)));
typedef unsigned int u32x4 __attribute__((ext_vector_type(4)));
typedef unsigned int u32x2 __attribute__((ext_vector_type(2)));

#define NN 512
#define LL 40
#define DD 128
#define OO 256
#define KK 9
#define MHCL 34
#define TT 32
#define PSTR 136   // pept LDS row stride (u16) -- fallback kernel only
#define KDSTR 72   // kern_s row stride (u16): 64 d + 8 pad
#define WPADL 64   // padded l-dim in preconverted W

#define PEPT_U16 (LL * PSTR)    // fallback only
#define KS_U16   (32 * KDSTR)   // 2304 u16 = 4608 B per-wave kern scratch

__device__ __forceinline__ u16 f2bf(float x) {
    unsigned int u = __builtin_bit_cast(unsigned int, x);
    u = (u + 0x7FFFu + ((u >> 16) & 1u)) >> 16;
    return (u16)u;
}
__device__ __forceinline__ u32 pk2(float a, float b) {
    __hip_bfloat162 h = __float22bfloat162_rn(make_float2(a, b)); // x = low half
    u32 r;
    __builtin_memcpy(&r, &h, 4);
    return r;
}
__device__ __forceinline__ bf16x8 ld8(const u16* p) {   // LDS or global, 16B
    u32x4 r;
    __builtin_memcpy(&r, __builtin_assume_aligned(p, 16), 16);
    return __builtin_bit_cast(bf16x8, r);
}
__device__ __forceinline__ f32x4 mfma16(bf16x8 a, bf16x8 b, f32x4 c) {
    return __builtin_amdgcn_mfma_f32_16x16x32_bf16(a, b, c, 0, 0, 0);
}

// prologue 1: W fp32 [O][K][34] -> bf16 zero-padded [O][K][64] in ws
__global__ void w_convert(const float* __restrict__ wgt, u32* __restrict__ wp) {
    int i = blockIdx.x * 256 + threadIdx.x;        // 36864 u32 outputs
    if (i >= OO * KK * (WPADL / 2)) return;
    int o = i / (KK * (WPADL / 2));
    int r = i - o * (KK * (WPADL / 2));
    int k = r >> 5;
    int lp = (r & 31) << 1;
    const float* src = wgt + ((size_t)o * KK + k) * MHCL;
    float a = (lp     < MHCL) ? src[lp]     : 0.f;
    float b = (lp + 1 < MHCL) ? src[lp + 1] : 0.f;
    wp[i] = pk2(a, b);
}

// prologue 2: pept fp32 [N][L][D] -> bf16 same layout in ws (5.24 MB)
__global__ void p_convert(const float* __restrict__ pept, u32* __restrict__ pp) {
    size_t i = (size_t)blockIdx.x * 256 + threadIdx.x;   // u32 pairs
    if (i >= (size_t)NN * LL * DD / 2) return;
    pp[i] = pk2(pept[2 * i], pept[2 * i + 1]);
}

// R11 = R10 with the spill fixed. R10's launch_bounds(256,6) capped the
// UNIFIED VGPR+AGPR file at 85 < demand (~100: 56 arch + 32 acc + addr) ->
// scratch spill (R1 signature: WRITE 16->69MB, FETCH 38->147MB, reported
// VGPR fell to 40, dur x2.5). The structural edit (pept->global, zero-barrier
// drift loop) was never cleanly tested. Here: cap 128 (256,4) -- R9's proven
// regime -- LDS stays 18.4KB so blocks/CU are VGPR-limited not LDS-limited.
__global__ __launch_bounds__(256, 4)
void iconv_fast(const float* __restrict__ mhc,
                const u16* __restrict__ wp,
                const u16* __restrict__ pb,
                const float* __restrict__ bias,
                float* __restrict__ out)
{
    // LDS 18432 B: 4 x wave-private kern_s[32 o'][72]
    // (kern_s doubles as the pair's acc-exchange buffer in the epilogue).
    __shared__ __align__(16) u16 s_ks[4 * KS_U16];

    const int tid  = threadIdx.x;
    const int wave = tid >> 6;
    const int pair = wave >> 1;     // pair index within block (0,1)
    const int dh   = wave & 1;      // d-half owner: d in [dh*64, dh*64+64)
    const int lane = tid & 63;
    const int quad = lane >> 4;
    const int l16  = lane & 15;

    const int n  = blockIdx.x >> 2;     // 4 blocks per sample
    const int oq = blockIdx.x & 3;      // o-quarter: chunks {oq*2, oq*2+1}
    const int obase = (oq * 2 + pair) * 32;   // this pair's single o-chunk

    u16* const ks = s_ks + wave * KS_U16;   // wave-private

    auto loadW = [&](int o_base, int k, bf16x8 wF[2][2]) {
        #pragma unroll
        for (int mt = 0; mt < 2; ++mt) {
            const u16* wr = wp + ((size_t)(o_base + mt * 16 + l16) * KK + k) * WPADL;
            u32x4 r0, r1;
            __builtin_memcpy(&r0, __builtin_assume_aligned(wr + quad * 8, 16), 16);
            __builtin_memcpy(&r1, __builtin_assume_aligned(wr + 32 + quad * 8, 16), 16);
            wF[mt][0] = __builtin_bit_cast(bf16x8, r0);
            wF[mt][1] = __builtin_bit_cast(bf16x8, r1);
        }
    };

    // first W fragments in flight under the mA build
    bf16x8 wB[2][2];
    loadW(obase, 0, wB);

    // ---- mA fragments DIRECT from global (no LDS, no barrier) ----
    // mA[di][ki] = mhc[l = ki*32 + quad*8 + j][d = dh*64 + di*16 + l16], bf16;
    // l >= MHCL are zero: slice ki=1 has only l=32,33 real (quad==0, j<2).
    bf16x8 mA[4][2];
    {
        const float* mg = mhc + (size_t)n * MHCL * DD;
        #pragma unroll
        for (int di = 0; di < 4; ++di) {
            const int d = dh * 64 + di * 16 + l16;
            u16 h0[8];
            #pragma unroll
            for (int j = 0; j < 8; ++j)
                h0[j] = f2bf(mg[(size_t)(quad * 8 + j) * DD + d]);
            __builtin_memcpy(&mA[di][0], h0, 16);
            u16 h1[8] = {0,0,0,0,0,0,0,0};
            if (quad == 0) {
                h1[0] = f2bf(mg[(size_t)32 * DD + d]);
                h1[1] = f2bf(mg[(size_t)33 * DD + d]);
            }
            __builtin_memcpy(&mA[di][1], h1, 16);
        }
    }

    const u16* const pr = pb + (size_t)n * LL * DD;   // this sample's bf16 pept

    // acc[ti][oj]: out[t = ti*16 + quad*4 + r][o' = oj*16 + l16], partial over this d-half
    f32x4 acc00 = {0.f,0.f,0.f,0.f}, acc01 = acc00, acc10 = acc00, acc11 = acc00;

    // ZERO-barrier drift k-loop: all LDS deps same-wave (private scratch);
    // pept A-frags straight from global bf16 (imm-offset foldable, L2-hot).
    #pragma unroll 3
    for (int k = 0; k < KK; ++k) {
        // stage1: kern[o'=32][d_local=64] for this k -> private scratch
        #pragma unroll
        for (int di = 0; di < 4; ++di) {
            f32x4 c0 = {0.f,0.f,0.f,0.f}, c1 = c0;
            c0 = mfma16(mA[di][0], wB[0][0], c0);   // C[d][o' 0..15]
            c0 = mfma16(mA[di][1], wB[0][1], c0);
            c1 = mfma16(mA[di][0], wB[1][0], c1);   // C[d][o' 16..31]
            c1 = mfma16(mA[di][1], wB[1][1], c1);
            u32x2 p0 = { pk2(fmaxf(c0[0], 0.f), fmaxf(c0[1], 0.f)),
                         pk2(fmaxf(c0[2], 0.f), fmaxf(c0[3], 0.f)) };
            u32x2 p1 = { pk2(fmaxf(c1[0], 0.f), fmaxf(c1[1], 0.f)),
                         pk2(fmaxf(c1[2], 0.f), fmaxf(c1[3], 0.f)) };
            __builtin_memcpy(__builtin_assume_aligned(&ks[l16 * KDSTR + di * 16 + quad * 4], 8), &p0, 8);
            __builtin_memcpy(__builtin_assume_aligned(&ks[(16 + l16) * KDSTR + di * 16 + quad * 4], 8), &p1, 8);
        }
        // refill wB (fully consumed by stage1 above); latency covered by stage2
        if (k < KK - 1) loadW(obase, k + 1, wB);
        // stage2: acc += pept[t][d] * kern[d][o'], kdim = 64 in 2 slices
        #pragma unroll
        for (int ds = 0; ds < 2; ++ds) {
            bf16x8 kb0 = ld8(&ks[l16 * KDSTR + ds * 32 + quad * 8]);
            bf16x8 kb1 = ld8(&ks[(16 + l16) * KDSTR + ds * 32 + quad * 8]);
            bf16x8 ap0 = ld8(&pr[(size_t)(k + l16) * DD + dh * 64 + ds * 32 + quad * 8]);
            bf16x8 ap1 = ld8(&pr[(size_t)(k + 16 + l16) * DD + dh * 64 + ds * 32 + quad * 8]);
            acc00 = mfma16(ap0, kb0, acc00);
            acc01 = mfma16(ap0, kb1, acc01);
            acc10 = mfma16(ap1, kb0, acc10);
            acc11 = mfma16(ap1, kb1, acc11);
        }
    }

    // ---- pair reduction: odd wave parks acc in its own scratch; even sums+stores ----
    if (dh == 1) {
        float* ox = (float*)ks;            // 64 lanes x 16 f32 = 4096 B <= 4608
        const int fb = lane * 16;
        __builtin_memcpy(__builtin_assume_aligned(&ox[fb +  0], 16), &acc00, 16);
        __builtin_memcpy(__builtin_assume_aligned(&ox[fb +  4], 16), &acc01, 16);
        __builtin_memcpy(__builtin_assume_aligned(&ox[fb +  8], 16), &acc10, 16);
        __builtin_memcpy(__builtin_assume_aligned(&ox[fb + 12], 16), &acc11, 16);
    }
    __syncthreads();
    if (dh == 0) {
        const float* px = (const float*)(s_ks + (wave + 1) * KS_U16);
        const int fb = lane * 16;
        f32x4 q00, q01, q10, q11;
        __builtin_memcpy(&q00, __builtin_assume_aligned(&px[fb +  0], 16), 16);
        __builtin_memcpy(&q01, __builtin_assume_aligned(&px[fb +  4], 16), 16);
        __builtin_memcpy(&q10, __builtin_assume_aligned(&px[fb +  8], 16), 16);
        __builtin_memcpy(&q11, __builtin_assume_aligned(&px[fb + 12], 16), 16);
        const float bv0 = bias[obase + l16];
        const float bv1 = bias[obase + 16 + l16];
        f32x4 r00 = acc00 + q00 + bv0;
        f32x4 r01 = acc01 + q01 + bv1;
        f32x4 r10 = acc10 + q10 + bv0;
        f32x4 r11 = acc11 + q11 + bv1;
        float* ob = out + ((size_t)n * OO + obase) * TT;
        __builtin_memcpy(__builtin_assume_aligned(ob + (size_t)l16 * TT + quad * 4, 16), &r00, 16);
        __builtin_memcpy(__builtin_assume_aligned(ob + (size_t)(16 + l16) * TT + quad * 4, 16), &r01, 16);
        __builtin_memcpy(__builtin_assume_aligned(ob + (size_t)l16 * TT + 16 + quad * 4, 16), &r10, 16);
        __builtin_memcpy(__builtin_assume_aligned(ob + (size_t)(16 + l16) * TT + 16 + quad * 4, 16), &r11, 16);
    }
}

// ---------- fallback (ws too small): R9 kernel, fp32 paths, LDS pept ----------
__global__ __launch_bounds__(256, 2)
void iconv_ref(const float* __restrict__ pept,
               const float* __restrict__ mhc,
               const float* __restrict__ wgt,
               const float* __restrict__ bias,
               float* __restrict__ out)
{
    __shared__ __align__(16) u16 s_mem[PEPT_U16 + 4 * KS_U16];
    const int tid  = threadIdx.x;
    const int wave = tid >> 6;
    const int pair = wave >> 1;
    const int dh   = wave & 1;
    const int lane = tid & 63;
    const int quad = lane >> 4;
    const int l16  = lane & 15;
    const int n  = blockIdx.x >> 2;
    const int oq = blockIdx.x & 3;
    const int obase = (oq * 2 + pair) * 32;
    u16* const s_pept = s_mem;
    u16* const ks     = s_mem + PEPT_U16 + wave * KS_U16;

    auto loadW = [&](int o_base, int k, bf16x8 wF[2][2]) {
        #pragma unroll
        for (int mt = 0; mt < 2; ++mt) {
            const float* wrow = wgt + ((size_t)(o_base + mt * 16 + l16) * KK + k) * MHCL;
            float w8[8];
            __builtin_memcpy(w8, __builtin_assume_aligned(wrow + quad * 8, 8), 32);
            u16 h0[8];
            #pragma unroll
            for (int j = 0; j < 8; ++j) h0[j] = f2bf(w8[j]);
            __builtin_memcpy(&wF[mt][0], h0, 16);
            u16 h1[8] = {0,0,0,0,0,0,0,0};
            if (quad == 0) { h1[0] = f2bf(wrow[32]); h1[1] = f2bf(wrow[33]); }
            __builtin_memcpy(&wF[mt][1], h1, 16);
        }
    };

    bf16x8 wB[2][2];
    loadW(obase, 0, wB);

    bf16x8 mA[4][2];
    {
        const float* mg = mhc + (size_t)n * MHCL * DD;
        #pragma unroll
        for (int di = 0; di < 4; ++di) {
            const int d = dh * 64 + di * 16 + l16;
            u16 h0[8];
            #pragma unroll
            for (int j = 0; j < 8; ++j)
                h0[j] = f2bf(mg[(size_t)(quad * 8 + j) * DD + d]);
            __builtin_memcpy(&mA[di][0], h0, 16);
            u16 h1[8] = {0,0,0,0,0,0,0,0};
            if (quad == 0) {
                h1[0] = f2bf(mg[(size_t)32 * DD + d]);
                h1[1] = f2bf(mg[(size_t)33 * DD + d]);
            }
            __builtin_memcpy(&mA[di][1], h1, 16);
        }
    }

    {
        const float* pg = pept + (size_t)n * LL * DD;
        #pragma unroll 1
        for (int i = tid; i < (LL * DD) / 4; i += 256) {
            int row = i >> 5, c4 = (i & 31) << 2;
            f32x4 v;
            __builtin_memcpy(&v, __builtin_assume_aligned(pg + row * DD + c4, 16), 16);
            u32x2 h = { pk2(v[0], v[1]), pk2(v[2], v[3]) };
            __builtin_memcpy(__builtin_assume_aligned(&s_pept[row * PSTR + c4], 8), &h, 8);
        }
    }
    __syncthreads();

    f32x4 acc00 = {0.f,0.f,0.f,0.f}, acc01 = acc00, acc10 = acc00, acc11 = acc00;

    #pragma unroll 3
    for (int k = 0; k < KK; ++k) {
        #pragma unroll
        for (int di = 0; di < 4; ++di) {
            f32x4 c0 = {0.f,0.f,0.f,0.f}, c1 = c0;
            c0 = mfma16(mA[di][0], wB[0][0], c0);
            c0 = mfma16(mA[di][1], wB[0][1], c0);
            c1 = mfma16(mA[di][0], wB[1][0], c1);
            c1 = mfma16(mA[di][1], wB[1][1], c1);
            u32x2 p0 = { pk2(fmaxf(c0[0], 0.f), fmaxf(c0[1], 0.f)),
                         pk2(fmaxf(c0[2], 0.f), fmaxf(c0[3], 0.f)) };
            u32x2 p1 = { pk2(fmaxf(c1[0], 0.f), fmaxf(c1[1], 0.f)),
                         pk2(fmaxf(c1[2], 0.f), fmaxf(c1[3], 0.f)) };
            __builtin_memcpy(__builtin_assume_aligned(&ks[l16 * KDSTR + di * 16 + quad * 4], 8), &p0, 8);
            __builtin_memcpy(__builtin_assume_aligned(&ks[(16 + l16) * KDSTR + di * 16 + quad * 4], 8), &p1, 8);
        }
        if (k < KK - 1) loadW(obase, k + 1, wB);
        #pragma unroll
        for (int ds = 0; ds < 2; ++ds) {
            bf16x8 kb0 = ld8(&ks[l16 * KDSTR + ds * 32 + quad * 8]);
            bf16x8 kb1 = ld8(&ks[(16 + l16) * KDSTR + ds * 32 + quad * 8]);
            bf16x8 ap0 = ld8(&s_pept[(k + l16) * PSTR + dh * 64 + ds * 32 + quad * 8]);
            bf16x8 ap1 = ld8(&s_pept[(k + 16 + l16) * PSTR + dh * 64 + ds * 32 + quad * 8]);
            acc00 = mfma16(ap0, kb0, acc00);
            acc01 = mfma16(ap0, kb1, acc01);
            acc10 = mfma16(ap1, kb0, acc10);
            acc11 = mfma16(ap1, kb1, acc11);
        }
    }

    if (dh == 1) {
        float* ox = (float*)ks;
        const int fb = lane * 16;
        __builtin_memcpy(__builtin_assume_aligned(&ox[fb +  0], 16), &acc00, 16);
        __builtin_memcpy(__builtin_assume_aligned(&ox[fb +  4], 16), &acc01, 16);
        __builtin_memcpy(__builtin_assume_aligned(&ox[fb +  8], 16), &acc10, 16);
        __builtin_memcpy(__builtin_assume_aligned(&ox[fb + 12], 16), &acc11, 16);
    }
    __syncthreads();
    if (dh == 0) {
        const float* px = (const float*)(s_mem + PEPT_U16 + (wave + 1) * KS_U16);
        const int fb = lane * 16;
        f32x4 q00, q01, q10, q11;
        __builtin_memcpy(&q00, __builtin_assume_aligned(&px[fb +  0], 16), 16);
        __builtin_memcpy(&q01, __builtin_assume_aligned(&px[fb +  4], 16), 16);
        __builtin_memcpy(&q10, __builtin_assume_aligned(&px[fb +  8], 16), 16);
        __builtin_memcpy(&q11, __builtin_assume_aligned(&px[fb + 12], 16), 16);
        const float bv0 = bias[obase + l16];
        const float bv1 = bias[obase + 16 + l16];
        f32x4 r00 = acc00 + q00 + bv0;
        f32x4 r01 = acc01 + q01 + bv1;
        f32x4 r10 = acc10 + q10 + bv0;
        f32x4 r11 = acc11 + q11 + bv1;
        float* ob = out + ((size_t)n * OO + obase) * TT;
        __builtin_memcpy(__builtin_assume_aligned(ob + (size_t)l16 * TT + quad * 4, 16), &r00, 16);
        __builtin_memcpy(__builtin_assume_aligned(ob + (size_t)(16 + l16) * TT + quad * 4, 16), &r01, 16);
        __builtin_memcpy(__builtin_assume_aligned(ob + (size_t)l16 * TT + 16 + quad * 4, 16), &r10, 16);
        __builtin_memcpy(__builtin_assume_aligned(ob + (size_t)(16 + l16) * TT + 16 + quad * 4, 16), &r11, 16);
    }
}

extern "C" void kernel_launch(void* const* d_in, const int* in_sizes, int n_in,
                              void* d_out, int out_size, void* d_ws, size_t ws_size,
                              hipStream_t stream) {
    const float* pept = (const float*)d_in[0];
    const float* mhc  = (const float*)d_in[1];
    const float* wgt  = (const float*)d_in[2];
    const float* bias = (const float*)d_in[3];
    float* out = (float*)d_out;

    const size_t w_bytes = (size_t)OO * KK * WPADL * sizeof(u16);   // 294,912
    const size_t p_bytes = (size_t)NN * LL * DD * sizeof(u16);      // 5,242,880
    if (ws_size >= w_bytes + p_bytes) {
        u16* wp = (u16*)d_ws;
        u16* pp = (u16*)((char*)d_ws + w_bytes);
        w_convert<<<dim3((OO * KK * (WPADL / 2) + 255) / 256), dim3(256), 0, stream>>>(wgt, (u32*)wp);
        p_convert<<<dim3((NN * LL * DD / 2 + 255) / 256), dim3(256), 0, stream>>>(pept, (u32*)pp);
        iconv_fast<<<dim3(NN * 4), dim3(256), 0, stream>>>(mhc, wp, pp, bias, out);
    } else {
        iconv_ref<<<dim3(NN * 4), dim3(256), 0, stream>>>(pept, mhc, wgt, bias, out);
    }
}

// Round 12
// 119.018 us; speedup vs baseline: 1.6978x; 1.2459x over previous
//
#include <hip/hip_runtime.h>
#include <hip/hip_bf16.h>

typedef unsigned short u16;
typedef unsigned int u32;
typedef __bf16 bf16x8 __attribute__((ext_vector_type(8)));
typedef float f32x4 __attribute__((ext_vector_type(4)));
typedef unsigned int u32x4 __attribute__((ext_vector_type(4)));
typedef unsigned int u32x2 __attribute__((ext_vector_type(2)));

#define NN 512
#define LL 40
#define DD 128
#define OO 256
#define KK 9
#define MHCL 34
#define TT 32
#define PSTR 136   // pept LDS row stride (u16)
#define KDSTR 72   // kern_s row stride (u16): 64 d + 8 pad
#define WPADL 64   // padded l-dim in preconverted W

#define PEPT_U16 (LL * PSTR)    // 5440 u16 = 10880 B
#define KS_U16   (32 * KDSTR)   // 2304 u16 = 4608 B per-wave kern scratch

__device__ __forceinline__ u16 f2bf(float x) {
    unsigned int u = __builtin_bit_cast(unsigned int, x);
    u = (u + 0x7FFFu + ((u >> 16) & 1u)) >> 16;
    return (u16)u;
}
__device__ __forceinline__ u32 pk2(float a, float b) {
    __hip_bfloat162 h = __float22bfloat162_rn(make_float2(a, b)); // x = low half
    u32 r;
    __builtin_memcpy(&r, &h, 4);
    return r;
}
__device__ __forceinline__ bf16x8 ld8(const u16* p) {   // LDS or global, 16B
    u32x4 r;
    __builtin_memcpy(&r, __builtin_assume_aligned(p, 16), 16);
    return __builtin_bit_cast(bf16x8, r);
}
__device__ __forceinline__ f32x4 mfma16(bf16x8 a, bf16x8 b, f32x4 c) {
    return __builtin_amdgcn_mfma_f32_16x16x32_bf16(a, b, c, 0, 0, 0);
}

// prologue 1: W fp32 [O][K][34] -> bf16 zero-padded [O][K][64] in ws
__global__ void w_convert(const float* __restrict__ wgt, u32* __restrict__ wp) {
    int i = blockIdx.x * 256 + threadIdx.x;        // 36864 u32 outputs
    if (i >= OO * KK * (WPADL / 2)) return;
    int o = i / (KK * (WPADL / 2));
    int r = i - o * (KK * (WPADL / 2));
    int k = r >> 5;
    int lp = (r & 31) << 1;
    const float* src = wgt + ((size_t)o * KK + k) * MHCL;
    float a = (lp     < MHCL) ? src[lp]     : 0.f;
    float b = (lp + 1 < MHCL) ? src[lp + 1] : 0.f;
    wp[i] = pk2(a, b);
}

// prologue 2: pept fp32 [N][L][D] -> bf16 same layout in ws (5.24 MB)
__global__ void p_convert(const float* __restrict__ pept, u32* __restrict__ pp) {
    size_t i = (size_t)blockIdx.x * 256 + threadIdx.x;   // u32 pairs
    if (i >= (size_t)NN * LL * DD / 2) return;
    pp[i] = pk2(pept[2 * i], pept[2 * i + 1]);
}

// R12 = R9 engine (proven 54.5us: wave-private scratch, zero-barrier drift
// k-loop, LDS pept) + pept pre-converted to bf16 in ws so the staging loop is
// a pure 16B copy (20 cvt-iterations -> 2.5 copy-iterations per thread; bf16
// halves the 4x-per-sample re-read). R11 verdict: stage2 operands MUST stay
// in LDS (global-in-inner-loop cost +25us at ~3 waves/SIMD); global loads are
// fine once-per-wave (mA build stays direct-global fp32). No cap changes:
// launch_bounds(256,2), the R9/R11-proven no-spill regime.
__global__ __launch_bounds__(256, 2)
void iconv_fast(const float* __restrict__ mhc,
                const u16* __restrict__ wp,
                const u16* __restrict__ pb,
                const float* __restrict__ bias,
                float* __restrict__ out)
{
    // LDS 29312 B: pept[40][136] | 4 x wave-private kern_s[32 o'][72]
    // (kern_s doubles as the pair's acc-exchange buffer in the epilogue).
    __shared__ __align__(16) u16 s_mem[PEPT_U16 + 4 * KS_U16];

    const int tid  = threadIdx.x;
    const int wave = tid >> 6;
    const int pair = wave >> 1;     // pair index within block (0,1)
    const int dh   = wave & 1;      // d-half owner: d in [dh*64, dh*64+64)
    const int lane = tid & 63;
    const int quad = lane >> 4;
    const int l16  = lane & 15;

    const int n  = blockIdx.x >> 2;     // 4 blocks per sample
    const int oq = blockIdx.x & 3;      // o-quarter: chunks {oq*2, oq*2+1}
    const int obase = (oq * 2 + pair) * 32;   // this pair's single o-chunk

    u16* const s_pept = s_mem;
    u16* const ks     = s_mem + PEPT_U16 + wave * KS_U16;   // wave-private

    auto loadW = [&](int o_base, int k, bf16x8 wF[2][2]) {
        #pragma unroll
        for (int mt = 0; mt < 2; ++mt) {
            const u16* wr = wp + ((size_t)(o_base + mt * 16 + l16) * KK + k) * WPADL;
            u32x4 r0, r1;
            __builtin_memcpy(&r0, __builtin_assume_aligned(wr + quad * 8, 16), 16);
            __builtin_memcpy(&r1, __builtin_assume_aligned(wr + 32 + quad * 8, 16), 16);
            wF[mt][0] = __builtin_bit_cast(bf16x8, r0);
            wF[mt][1] = __builtin_bit_cast(bf16x8, r1);
        }
    };

    // first W fragments in flight under the prologue
    bf16x8 wB[2][2];
    loadW(obase, 0, wB);

    // ---- mA fragments DIRECT from global fp32 (once per wave, amortized) ----
    // mA[di][ki] = mhc[l = ki*32 + quad*8 + j][d = dh*64 + di*16 + l16], bf16;
    // l >= MHCL are zero: slice ki=1 has only l=32,33 real (quad==0, j<2).
    bf16x8 mA[4][2];
    {
        const float* mg = mhc + (size_t)n * MHCL * DD;
        #pragma unroll
        for (int di = 0; di < 4; ++di) {
            const int d = dh * 64 + di * 16 + l16;
            u16 h0[8];
            #pragma unroll
            for (int j = 0; j < 8; ++j)
                h0[j] = f2bf(mg[(size_t)(quad * 8 + j) * DD + d]);
            __builtin_memcpy(&mA[di][0], h0, 16);
            u16 h1[8] = {0,0,0,0,0,0,0,0};
            if (quad == 0) {
                h1[0] = f2bf(mg[(size_t)32 * DD + d]);
                h1[1] = f2bf(mg[(size_t)33 * DD + d]);
            }
            __builtin_memcpy(&mA[di][1], h1, 16);
        }
    }

    // ---- pept staging: pure 16B bf16 copy from ws (no conversion VALU) ----
    {
        const u16* pg = pb + (size_t)n * LL * DD;
        #pragma unroll 1
        for (int i = tid; i < (LL * DD) / 8; i += 256) {   // 640 16B chunks
            int row = i >> 4, c8 = (i & 15) << 3;
            u32x4 v;
            __builtin_memcpy(&v, __builtin_assume_aligned(pg + (size_t)row * DD + c8, 16), 16);
            __builtin_memcpy(__builtin_assume_aligned(&s_pept[row * PSTR + c8], 16), &v, 16);
        }
    }
    __syncthreads();

    // acc[ti][oj]: out[t = ti*16 + quad*4 + r][o' = oj*16 + l16], partial over this d-half
    f32x4 acc00 = {0.f,0.f,0.f,0.f}, acc01 = acc00, acc10 = acc00, acc11 = acc00;

    // barrier-free drift k-loop: all LDS deps same-wave (private scratch)
    #pragma unroll 3
    for (int k = 0; k < KK; ++k) {
        // stage1: kern[o'=32][d_local=64] for this k -> private scratch
        #pragma unroll
        for (int di = 0; di < 4; ++di) {
            f32x4 c0 = {0.f,0.f,0.f,0.f}, c1 = c0;
            c0 = mfma16(mA[di][0], wB[0][0], c0);   // C[d][o' 0..15]
            c0 = mfma16(mA[di][1], wB[0][1], c0);
            c1 = mfma16(mA[di][0], wB[1][0], c1);   // C[d][o' 16..31]
            c1 = mfma16(mA[di][1], wB[1][1], c1);
            u32x2 p0 = { pk2(fmaxf(c0[0], 0.f), fmaxf(c0[1], 0.f)),
                         pk2(fmaxf(c0[2], 0.f), fmaxf(c0[3], 0.f)) };
            u32x2 p1 = { pk2(fmaxf(c1[0], 0.f), fmaxf(c1[1], 0.f)),
                         pk2(fmaxf(c1[2], 0.f), fmaxf(c1[3], 0.f)) };
            __builtin_memcpy(__builtin_assume_aligned(&ks[l16 * KDSTR + di * 16 + quad * 4], 8), &p0, 8);
            __builtin_memcpy(__builtin_assume_aligned(&ks[(16 + l16) * KDSTR + di * 16 + quad * 4], 8), &p1, 8);
        }
        // refill wB (fully consumed by stage1 above); latency covered by stage2
        if (k < KK - 1) loadW(obase, k + 1, wB);
        // stage2: acc += pept[t][d] * kern[d][o'], kdim = 64 in 2 slices
        #pragma unroll
        for (int ds = 0; ds < 2; ++ds) {
            bf16x8 kb0 = ld8(&ks[l16 * KDSTR + ds * 32 + quad * 8]);
            bf16x8 kb1 = ld8(&ks[(16 + l16) * KDSTR + ds * 32 + quad * 8]);
            bf16x8 ap0 = ld8(&s_pept[(k + l16) * PSTR + dh * 64 + ds * 32 + quad * 8]);
            bf16x8 ap1 = ld8(&s_pept[(k + 16 + l16) * PSTR + dh * 64 + ds * 32 + quad * 8]);
            acc00 = mfma16(ap0, kb0, acc00);
            acc01 = mfma16(ap0, kb1, acc01);
            acc10 = mfma16(ap1, kb0, acc10);
            acc11 = mfma16(ap1, kb1, acc11);
        }
    }

    // ---- pair reduction: odd wave parks acc in its own scratch; even sums+stores ----
    if (dh == 1) {
        float* ox = (float*)ks;            // 64 lanes x 16 f32 = 4096 B <= 4608
        const int fb = lane * 16;
        __builtin_memcpy(__builtin_assume_aligned(&ox[fb +  0], 16), &acc00, 16);
        __builtin_memcpy(__builtin_assume_aligned(&ox[fb +  4], 16), &acc01, 16);
        __builtin_memcpy(__builtin_assume_aligned(&ox[fb +  8], 16), &acc10, 16);
        __builtin_memcpy(__builtin_assume_aligned(&ox[fb + 12], 16), &acc11, 16);
    }
    __syncthreads();
    if (dh == 0) {
        const float* px = (const float*)(s_mem + PEPT_U16 + (wave + 1) * KS_U16);
        const int fb = lane * 16;
        f32x4 q00, q01, q10, q11;
        __builtin_memcpy(&q00, __builtin_assume_aligned(&px[fb +  0], 16), 16);
        __builtin_memcpy(&q01, __builtin_assume_aligned(&px[fb +  4], 16), 16);
        __builtin_memcpy(&q10, __builtin_assume_aligned(&px[fb +  8], 16), 16);
        __builtin_memcpy(&q11, __builtin_assume_aligned(&px[fb + 12], 16), 16);
        const float bv0 = bias[obase + l16];
        const float bv1 = bias[obase + 16 + l16];
        f32x4 r00 = acc00 + q00 + bv0;
        f32x4 r01 = acc01 + q01 + bv1;
        f32x4 r10 = acc10 + q10 + bv0;
        f32x4 r11 = acc11 + q11 + bv1;
        float* ob = out + ((size_t)n * OO + obase) * TT;
        __builtin_memcpy(__builtin_assume_aligned(ob + (size_t)l16 * TT + quad * 4, 16), &r00, 16);
        __builtin_memcpy(__builtin_assume_aligned(ob + (size_t)(16 + l16) * TT + quad * 4, 16), &r01, 16);
        __builtin_memcpy(__builtin_assume_aligned(ob + (size_t)l16 * TT + 16 + quad * 4, 16), &r10, 16);
        __builtin_memcpy(__builtin_assume_aligned(ob + (size_t)(16 + l16) * TT + 16 + quad * 4, 16), &r11, 16);
    }
}

// ---------- fallback (ws too small): full fp32 path, LDS pept (R9 shape) ----------
__global__ __launch_bounds__(256, 2)
void iconv_ref(const float* __restrict__ pept,
               const float* __restrict__ mhc,
               const float* __restrict__ wgt,
               const float* __restrict__ bias,
               float* __restrict__ out)
{
    __shared__ __align__(16) u16 s_mem[PEPT_U16 + 4 * KS_U16];
    const int tid  = threadIdx.x;
    const int wave = tid >> 6;
    const int pair = wave >> 1;
    const int dh   = wave & 1;
    const int lane = tid & 63;
    const int quad = lane >> 4;
    const int l16  = lane & 15;
    const int n  = blockIdx.x >> 2;
    const int oq = blockIdx.x & 3;
    const int obase = (oq * 2 + pair) * 32;
    u16* const s_pept = s_mem;
    u16* const ks     = s_mem + PEPT_U16 + wave * KS_U16;

    auto loadW = [&](int o_base, int k, bf16x8 wF[2][2]) {
        #pragma unroll
        for (int mt = 0; mt < 2; ++mt) {
            const float* wrow = wgt + ((size_t)(o_base + mt * 16 + l16) * KK + k) * MHCL;
            float w8[8];
            __builtin_memcpy(w8, __builtin_assume_aligned(wrow + quad * 8, 8), 32);
            u16 h0[8];
            #pragma unroll
            for (int j = 0; j < 8; ++j) h0[j] = f2bf(w8[j]);
            __builtin_memcpy(&wF[mt][0], h0, 16);
            u16 h1[8] = {0,0,0,0,0,0,0,0};
            if (quad == 0) { h1[0] = f2bf(wrow[32]); h1[1] = f2bf(wrow[33]); }
            __builtin_memcpy(&wF[mt][1], h1, 16);
        }
    };

    bf16x8 wB[2][2];
    loadW(obase, 0, wB);

    bf16x8 mA[4][2];
    {
        const float* mg = mhc + (size_t)n * MHCL * DD;
        #pragma unroll
        for (int di = 0; di < 4; ++di) {
            const int d = dh * 64 + di * 16 + l16;
            u16 h0[8];
            #pragma unroll
            for (int j = 0; j < 8; ++j)
                h0[j] = f2bf(mg[(size_t)(quad * 8 + j) * DD + d]);
            __builtin_memcpy(&mA[di][0], h0, 16);
            u16 h1[8] = {0,0,0,0,0,0,0,0};
            if (quad == 0) {
                h1[0] = f2bf(mg[(size_t)32 * DD + d]);
                h1[1] = f2bf(mg[(size_t)33 * DD + d]);
            }
            __builtin_memcpy(&mA[di][1], h1, 16);
        }
    }

    {
        const float* pg = pept + (size_t)n * LL * DD;
        #pragma unroll 1
        for (int i = tid; i < (LL * DD) / 4; i += 256) {
            int row = i >> 5, c4 = (i & 31) << 2;
            f32x4 v;
            __builtin_memcpy(&v, __builtin_assume_aligned(pg + row * DD + c4, 16), 16);
            u32x2 h = { pk2(v[0], v[1]), pk2(v[2], v[3]) };
            __builtin_memcpy(__builtin_assume_aligned(&s_pept[row * PSTR + c4], 8), &h, 8);
        }
    }
    __syncthreads();

    f32x4 acc00 = {0.f,0.f,0.f,0.f}, acc01 = acc00, acc10 = acc00, acc11 = acc00;

    #pragma unroll 3
    for (int k = 0; k < KK; ++k) {
        #pragma unroll
        for (int di = 0; di < 4; ++di) {
            f32x4 c0 = {0.f,0.f,0.f,0.f}, c1 = c0;
            c0 = mfma16(mA[di][0], wB[0][0], c0);
            c0 = mfma16(mA[di][1], wB[0][1], c0);
            c1 = mfma16(mA[di][0], wB[1][0], c1);
            c1 = mfma16(mA[di][1], wB[1][1], c1);
            u32x2 p0 = { pk2(fmaxf(c0[0], 0.f), fmaxf(c0[1], 0.f)),
                         pk2(fmaxf(c0[2], 0.f), fmaxf(c0[3], 0.f)) };
            u32x2 p1 = { pk2(fmaxf(c1[0], 0.f), fmaxf(c1[1], 0.f)),
                         pk2(fmaxf(c1[2], 0.f), fmaxf(c1[3], 0.f)) };
            __builtin_memcpy(__builtin_assume_aligned(&ks[l16 * KDSTR + di * 16 + quad * 4], 8), &p0, 8);
            __builtin_memcpy(__builtin_assume_aligned(&ks[(16 + l16) * KDSTR + di * 16 + quad * 4], 8), &p1, 8);
        }
        if (k < KK - 1) loadW(obase, k + 1, wB);
        #pragma unroll
        for (int ds = 0; ds < 2; ++ds) {
            bf16x8 kb0 = ld8(&ks[l16 * KDSTR + ds * 32 + quad * 8]);
            bf16x8 kb1 = ld8(&ks[(16 + l16) * KDSTR + ds * 32 + quad * 8]);
            bf16x8 ap0 = ld8(&s_pept[(k + l16) * PSTR + dh * 64 + ds * 32 + quad * 8]);
            bf16x8 ap1 = ld8(&s_pept[(k + 16 + l16) * PSTR + dh * 64 + ds * 32 + quad * 8]);
            acc00 = mfma16(ap0, kb0, acc00);
            acc01 = mfma16(ap0, kb1, acc01);
            acc10 = mfma16(ap1, kb0, acc10);
            acc11 = mfma16(ap1, kb1, acc11);
        }
    }

    if (dh == 1) {
        float* ox = (float*)ks;
        const int fb = lane * 16;
        __builtin_memcpy(__builtin_assume_aligned(&ox[fb +  0], 16), &acc00, 16);
        __builtin_memcpy(__builtin_assume_aligned(&ox[fb +  4], 16), &acc01, 16);
        __builtin_memcpy(__builtin_assume_aligned(&ox[fb +  8], 16), &acc10, 16);
        __builtin_memcpy(__builtin_assume_aligned(&ox[fb + 12], 16), &acc11, 16);
    }
    __syncthreads();
    if (dh == 0) {
        const float* px = (const float*)(s_mem + PEPT_U16 + (wave + 1) * KS_U16);
        const int fb = lane * 16;
        f32x4 q00, q01, q10, q11;
        __builtin_memcpy(&q00, __builtin_assume_aligned(&px[fb +  0], 16), 16);
        __builtin_memcpy(&q01, __builtin_assume_aligned(&px[fb +  4], 16), 16);
        __builtin_memcpy(&q10, __builtin_assume_aligned(&px[fb +  8], 16), 16);
        __builtin_memcpy(&q11, __builtin_assume_aligned(&px[fb + 12], 16), 16);
        const float bv0 = bias[obase + l16];
        const float bv1 = bias[obase + 16 + l16];
        f32x4 r00 = acc00 + q00 + bv0;
        f32x4 r01 = acc01 + q01 + bv1;
        f32x4 r10 = acc10 + q10 + bv0;
        f32x4 r11 = acc11 + q11 + bv1;
        float* ob = out + ((size_t)n * OO + obase) * TT;
        __builtin_memcpy(__builtin_assume_aligned(ob + (size_t)l16 * TT + quad * 4, 16), &r00, 16);
        __builtin_memcpy(__builtin_assume_aligned(ob + (size_t)(16 + l16) * TT + quad * 4, 16), &r01, 16);
        __builtin_memcpy(__builtin_assume_aligned(ob + (size_t)l16 * TT + 16 + quad * 4, 16), &r10, 16);
        __builtin_memcpy(__builtin_assume_aligned(ob + (size_t)(16 + l16) * TT + 16 + quad * 4, 16), &r11, 16);
    }
}

extern "C" void kernel_launch(void* const* d_in, const int* in_sizes, int n_in,
                              void* d_out, int out_size, void* d_ws, size_t ws_size,
                              hipStream_t stream) {
    const float* pept = (const float*)d_in[0];
    const float* mhc  = (const float*)d_in[1];
    const float* wgt  = (const float*)d_in[2];
    const float* bias = (const float*)d_in[3];
    float* out = (float*)d_out;

    const size_t w_bytes = (size_t)OO * KK * WPADL * sizeof(u16);   // 294,912
    const size_t p_bytes = (size_t)NN * LL * DD * sizeof(u16);      // 5,242,880
    if (ws_size >= w_bytes + p_bytes) {
        u16* wp = (u16*)d_ws;
        u16* pp = (u16*)((char*)d_ws + w_bytes);
        w_convert<<<dim3((OO * KK * (WPADL / 2) + 255) / 256), dim3(256), 0, stream>>>(wgt, (u32*)wp);
        p_convert<<<dim3((NN * LL * DD / 2 + 255) / 256), dim3(256), 0, stream>>>(pept, (u32*)pp);
        iconv_fast<<<dim3(NN * 4), dim3(256), 0, stream>>>(mhc, wp, pp, bias, out);
    } else {
        iconv_ref<<<dim3(NN * 4), dim3(256), 0, stream>>>(pept, mhc, wgt, bias, out);
    }
}

// Round 13
// 117.010 us; speedup vs baseline: 1.7269x; 1.0172x over previous
//
#include <hip/hip_runtime.h>
#include <hip/hip_bf16.h>

typedef unsigned short u16;
typedef unsigned int u32;
typedef __bf16 bf16x8 __attribute__((ext_vector_type(8)));
typedef float f32x4 __attribute__((ext_vector_type(4)));
typedef unsigned int u32x4 __attribute__((ext_vector_type(4)));
typedef unsigned int u32x2 __attribute__((ext_vector_type(2)));

#define NN 512
#define LL 40
#define DD 128
#define OO 256
#define KK 9
#define MHCL 34
#define TT 32
#define PSTR 136   // pept LDS row stride (u16)
#define KDSTR 72   // kern_s row stride (fallback kernel only)
#define WPADL 64   // padded l-dim in preconverted W

#define PEPT_U16 (LL * PSTR)    // 5440 u16 = 10880 B
#define KS_U16   (32 * KDSTR)   // fallback only
#define EX_U16   2048           // pair exchange buffer: 64 lanes x 16 f32 = 4096 B

__device__ __forceinline__ u16 f2bf(float x) {
    unsigned int u = __builtin_bit_cast(unsigned int, x);
    u = (u + 0x7FFFu + ((u >> 16) & 1u)) >> 16;
    return (u16)u;
}
__device__ __forceinline__ u32 pk2(float a, float b) {
    __hip_bfloat162 h = __float22bfloat162_rn(make_float2(a, b)); // x = low half
    u32 r;
    __builtin_memcpy(&r, &h, 4);
    return r;
}
__device__ __forceinline__ bf16x8 ld8(const u16* p) {   // LDS or global, 16B
    u32x4 r;
    __builtin_memcpy(&r, __builtin_assume_aligned(p, 16), 16);
    return __builtin_bit_cast(bf16x8, r);
}
__device__ __forceinline__ f32x4 mfma16(bf16x8 a, bf16x8 b, f32x4 c) {
    return __builtin_amdgcn_mfma_f32_16x16x32_bf16(a, b, c, 0, 0, 0);
}

// fused prologue: W fp32 [O][K][34] -> bf16 [O][K][64] padded, AND
// pept fp32 [N][L][D] -> bf16 same layout. One dispatch (was two: the extra
// launch ate R12's in-kernel gain on the bench).
__global__ void cvt_all(const float* __restrict__ wgt, const float* __restrict__ pept,
                        u32* __restrict__ wp, u32* __restrict__ pp) {
    int i = blockIdx.x * 256 + threadIdx.x;
    const int WN = OO * KK * (WPADL / 2);            // 36864
    if (i < WN) {
        int o = i / (KK * (WPADL / 2));
        int r = i - o * (KK * (WPADL / 2));
        int k = r >> 5;
        int lp = (r & 31) << 1;
        const float* src = wgt + ((size_t)o * KK + k) * MHCL;
        float a = (lp     < MHCL) ? src[lp]     : 0.f;
        float b = (lp + 1 < MHCL) ? src[lp + 1] : 0.f;
        wp[i] = pk2(a, b);
    } else {
        size_t j = (size_t)(i - WN);
        if (j < (size_t)NN * LL * DD / 2)
            pp[j] = pk2(pept[2 * j], pept[2 * j + 1]);
    }
}

// R13: IN-REGISTER KERN via mA row permutation. R12 (49.8us): remaining
// per-k serial segment = stage1 pack -> ds_write -> ds_read -> stage2 MFMA
// (~240cy RAW). Key identity: stage1's C layout gives lane(q,l16) the pair
// d=16di+4q+r; stage2's B-frag wants d=32ds+8q+j at the same lane. Building
// mA with the permutation d(di, m=4q+r) = dh*64 + 32(di&1) + 8q + 4(di>>1)+r
// makes stage1's packed output registers BE stage2's B-operands:
//   bk0[ds] = {kc0[ds].xy, kc0[ds+2].xy}   (zero data movement).
// Kern LDS buffer + 8 ds_write + 4 ds_read per k-step all deleted. LDS
// 29.3KB -> 19.1KB (pept + 8KB pair-exchange). launch_bounds stays (256,2)
// (R1/R10: never cap below unified VGPR+AGPR demand).
__global__ __launch_bounds__(256, 2)
void iconv_fast(const float* __restrict__ mhc,
                const u16* __restrict__ wp,
                const u16* __restrict__ pb,
                const float* __restrict__ bias,
                float* __restrict__ out)
{
    // LDS 19072 B: pept[40][136] | 2 x pair-exchange f32[64][16]
    __shared__ __align__(16) u16 s_mem[PEPT_U16 + 2 * EX_U16];

    const int tid  = threadIdx.x;
    const int wave = tid >> 6;
    const int pair = wave >> 1;     // pair index within block (0,1)
    const int dh   = wave & 1;      // d-half owner: d in [dh*64, dh*64+64)
    const int lane = tid & 63;
    const int quad = lane >> 4;
    const int l16  = lane & 15;

    const int n  = blockIdx.x >> 2;     // 4 blocks per sample
    const int oq = blockIdx.x & 3;      // o-quarter: chunks {oq*2, oq*2+1}
    const int obase = (oq * 2 + pair) * 32;   // this pair's single o-chunk

    u16* const s_pept = s_mem;

    auto loadW = [&](int o_base, int k, bf16x8 wF[2][2]) {
        #pragma unroll
        for (int mt = 0; mt < 2; ++mt) {
            const u16* wr = wp + ((size_t)(o_base + mt * 16 + l16) * KK + k) * WPADL;
            u32x4 r0, r1;
            __builtin_memcpy(&r0, __builtin_assume_aligned(wr + quad * 8, 16), 16);
            __builtin_memcpy(&r1, __builtin_assume_aligned(wr + 32 + quad * 8, 16), 16);
            wF[mt][0] = __builtin_bit_cast(bf16x8, r0);
            wF[mt][1] = __builtin_bit_cast(bf16x8, r1);
        }
    };

    // first W fragments in flight under the prologue
    bf16x8 wB[2][2];
    loadW(obase, 0, wB);

    // ---- mA DIRECT from global fp32, with PERMUTED d-rows ----
    // A-frag row m (= l16) of sub-matrix di maps to
    //   d = dh*64 + 32*(di&1) + 8*(m>>2) + 4*(di>>1) + (m&3)
    // (bijective on [0,64): bits {5}=di&1, {4:3}=m>>2, {2}=di>>1, {1:0}=m&3).
    // Consequence: stage1 C at lane(q,l16), reg r covers d = 32(di&1)+8q+4(di>>1)+r,
    // exactly stage2's B-frag ordering.
    bf16x8 mA[4][2];
    {
        const float* mg = mhc + (size_t)n * MHCL * DD;
        #pragma unroll
        for (int di = 0; di < 4; ++di) {
            const int d = dh * 64 + 32 * (di & 1) + 8 * (l16 >> 2) + 4 * (di >> 1) + (l16 & 3);
            u16 h0[8];
            #pragma unroll
            for (int j = 0; j < 8; ++j)
                h0[j] = f2bf(mg[(size_t)(quad * 8 + j) * DD + d]);
            __builtin_memcpy(&mA[di][0], h0, 16);
            u16 h1[8] = {0,0,0,0,0,0,0,0};
            if (quad == 0) {
                h1[0] = f2bf(mg[(size_t)32 * DD + d]);
                h1[1] = f2bf(mg[(size_t)33 * DD + d]);
            }
            __builtin_memcpy(&mA[di][1], h1, 16);
        }
    }

    // ---- pept staging: pure 16B bf16 copy from ws ----
    {
        const u16* pg = pb + (size_t)n * LL * DD;
        #pragma unroll 1
        for (int i = tid; i < (LL * DD) / 8; i += 256) {   // 640 16B chunks
            int row = i >> 4, c8 = (i & 15) << 3;
            u32x4 v;
            __builtin_memcpy(&v, __builtin_assume_aligned(pg + (size_t)row * DD + c8, 16), 16);
            __builtin_memcpy(__builtin_assume_aligned(&s_pept[row * PSTR + c8], 16), &v, 16);
        }
    }
    __syncthreads();

    // acc[ti][oj]: out[t = ti*16 + quad*4 + r][o' = oj*16 + l16], partial over this d-half
    f32x4 acc00 = {0.f,0.f,0.f,0.f}, acc01 = acc00, acc10 = acc00, acc11 = acc00;

    // k-loop: stage1 -> registers -> stage2, zero LDS on the kern path,
    // zero barriers, wave-drift preserved.
    #pragma unroll 3
    for (int k = 0; k < KK; ++k) {
        // stage1: kern for this k, packed bf16 pairs in registers
        u32x2 kc0[4], kc1[4];
        #pragma unroll
        for (int di = 0; di < 4; ++di) {
            f32x4 c0 = {0.f,0.f,0.f,0.f}, c1 = c0;
            c0 = mfma16(mA[di][0], wB[0][0], c0);   // C[d(di,m)][o' 0..15]
            c0 = mfma16(mA[di][1], wB[0][1], c0);
            c1 = mfma16(mA[di][0], wB[1][0], c1);   // C[d(di,m)][o' 16..31]
            c1 = mfma16(mA[di][1], wB[1][1], c1);
            kc0[di][0] = pk2(fmaxf(c0[0], 0.f), fmaxf(c0[1], 0.f));
            kc0[di][1] = pk2(fmaxf(c0[2], 0.f), fmaxf(c0[3], 0.f));
            kc1[di][0] = pk2(fmaxf(c1[0], 0.f), fmaxf(c1[1], 0.f));
            kc1[di][1] = pk2(fmaxf(c1[2], 0.f), fmaxf(c1[3], 0.f));
        }
        // refill wB (fully consumed); latency covered by stage2
        if (k < KK - 1) loadW(obase, k + 1, wB);
        // stage2: B-frags assembled from stage1 registers (same lane)
        #pragma unroll
        for (int ds = 0; ds < 2; ++ds) {
            u32x4 b0 = { kc0[ds][0], kc0[ds][1], kc0[ds + 2][0], kc0[ds + 2][1] };
            u32x4 b1 = { kc1[ds][0], kc1[ds][1], kc1[ds + 2][0], kc1[ds + 2][1] };
            bf16x8 bk0 = __builtin_bit_cast(bf16x8, b0);
            bf16x8 bk1 = __builtin_bit_cast(bf16x8, b1);
            bf16x8 ap0 = ld8(&s_pept[(k + l16) * PSTR + dh * 64 + ds * 32 + quad * 8]);
            bf16x8 ap1 = ld8(&s_pept[(k + 16 + l16) * PSTR + dh * 64 + ds * 32 + quad * 8]);
            acc00 = mfma16(ap0, bk0, acc00);
            acc01 = mfma16(ap0, bk1, acc01);
            acc10 = mfma16(ap1, bk0, acc10);
            acc11 = mfma16(ap1, bk1, acc11);
        }
    }

    // ---- pair reduction: odd wave parks acc in pair buffer; even sums+stores ----
    if (dh == 1) {
        float* ox = (float*)(s_mem + PEPT_U16 + pair * EX_U16);
        const int fb = lane * 16;
        __builtin_memcpy(__builtin_assume_aligned(&ox[fb +  0], 16), &acc00, 16);
        __builtin_memcpy(__builtin_assume_aligned(&ox[fb +  4], 16), &acc01, 16);
        __builtin_memcpy(__builtin_assume_aligned(&ox[fb +  8], 16), &acc10, 16);
        __builtin_memcpy(__builtin_assume_aligned(&ox[fb + 12], 16), &acc11, 16);
    }
    __syncthreads();
    if (dh == 0) {
        const float* px = (const float*)(s_mem + PEPT_U16 + pair * EX_U16);
        const int fb = lane * 16;
        f32x4 q00, q01, q10, q11;
        __builtin_memcpy(&q00, __builtin_assume_aligned(&px[fb +  0], 16), 16);
        __builtin_memcpy(&q01, __builtin_assume_aligned(&px[fb +  4], 16), 16);
        __builtin_memcpy(&q10, __builtin_assume_aligned(&px[fb +  8], 16), 16);
        __builtin_memcpy(&q11, __builtin_assume_aligned(&px[fb + 12], 16), 16);
        const float bv0 = bias[obase + l16];
        const float bv1 = bias[obase + 16 + l16];
        f32x4 r00 = acc00 + q00 + bv0;
        f32x4 r01 = acc01 + q01 + bv1;
        f32x4 r10 = acc10 + q10 + bv0;
        f32x4 r11 = acc11 + q11 + bv1;
        float* ob = out + ((size_t)n * OO + obase) * TT;
        __builtin_memcpy(__builtin_assume_aligned(ob + (size_t)l16 * TT + quad * 4, 16), &r00, 16);
        __builtin_memcpy(__builtin_assume_aligned(ob + (size_t)(16 + l16) * TT + quad * 4, 16), &r01, 16);
        __builtin_memcpy(__builtin_assume_aligned(ob + (size_t)l16 * TT + 16 + quad * 4, 16), &r10, 16);
        __builtin_memcpy(__builtin_assume_aligned(ob + (size_t)(16 + l16) * TT + 16 + quad * 4, 16), &r11, 16);
    }
}

// ---------- fallback (ws too small): R12's fp32 path, LDS kern (proven) ----------
__global__ __launch_bounds__(256, 2)
void iconv_ref(const float* __restrict__ pept,
               const float* __restrict__ mhc,
               const float* __restrict__ wgt,
               const float* __restrict__ bias,
               float* __restrict__ out)
{
    __shared__ __align__(16) u16 s_mem[PEPT_U16 + 4 * KS_U16];
    const int tid  = threadIdx.x;
    const int wave = tid >> 6;
    const int dh   = wave & 1;
    const int lane = tid & 63;
    const int quad = lane >> 4;
    const int l16  = lane & 15;
    const int n  = blockIdx.x >> 2;
    const int oq = blockIdx.x & 3;
    const int obase = (oq * 2 + (wave >> 1)) * 32;
    u16* const s_pept = s_mem;
    u16* const ks     = s_mem + PEPT_U16 + wave * KS_U16;

    auto loadW = [&](int o_base, int k, bf16x8 wF[2][2]) {
        #pragma unroll
        for (int mt = 0; mt < 2; ++mt) {
            const float* wrow = wgt + ((size_t)(o_base + mt * 16 + l16) * KK + k) * MHCL;
            float w8[8];
            __builtin_memcpy(w8, __builtin_assume_aligned(wrow + quad * 8, 8), 32);
            u16 h0[8];
            #pragma unroll
            for (int j = 0; j < 8; ++j) h0[j] = f2bf(w8[j]);
            __builtin_memcpy(&wF[mt][0], h0, 16);
            u16 h1[8] = {0,0,0,0,0,0,0,0};
            if (quad == 0) { h1[0] = f2bf(wrow[32]); h1[1] = f2bf(wrow[33]); }
            __builtin_memcpy(&wF[mt][1], h1, 16);
        }
    };

    bf16x8 wB[2][2];
    loadW(obase, 0, wB);

    bf16x8 mA[4][2];
    {
        const float* mg = mhc + (size_t)n * MHCL * DD;
        #pragma unroll
        for (int di = 0; di < 4; ++di) {
            const int d = dh * 64 + di * 16 + l16;
            u16 h0[8];
            #pragma unroll
            for (int j = 0; j < 8; ++j)
                h0[j] = f2bf(mg[(size_t)(quad * 8 + j) * DD + d]);
            __builtin_memcpy(&mA[di][0], h0, 16);
            u16 h1[8] = {0,0,0,0,0,0,0,0};
            if (quad == 0) {
                h1[0] = f2bf(mg[(size_t)32 * DD + d]);
                h1[1] = f2bf(mg[(size_t)33 * DD + d]);
            }
            __builtin_memcpy(&mA[di][1], h1, 16);
        }
    }

    {
        const float* pg = pept + (size_t)n * LL * DD;
        #pragma unroll 1
        for (int i = tid; i < (LL * DD) / 4; i += 256) {
            int row = i >> 5, c4 = (i & 31) << 2;
            f32x4 v;
            __builtin_memcpy(&v, __builtin_assume_aligned(pg + row * DD + c4, 16), 16);
            u32x2 h = { pk2(v[0], v[1]), pk2(v[2], v[3]) };
            __builtin_memcpy(__builtin_assume_aligned(&s_pept[row * PSTR + c4], 8), &h, 8);
        }
    }
    __syncthreads();

    f32x4 acc00 = {0.f,0.f,0.f,0.f}, acc01 = acc00, acc10 = acc00, acc11 = acc00;

    #pragma unroll 3
    for (int k = 0; k < KK; ++k) {
        #pragma unroll
        for (int di = 0; di < 4; ++di) {
            f32x4 c0 = {0.f,0.f,0.f,0.f}, c1 = c0;
            c0 = mfma16(mA[di][0], wB[0][0], c0);
            c0 = mfma16(mA[di][1], wB[0][1], c0);
            c1 = mfma16(mA[di][0], wB[1][0], c1);
            c1 = mfma16(mA[di][1], wB[1][1], c1);
            u32x2 p0 = { pk2(fmaxf(c0[0], 0.f), fmaxf(c0[1], 0.f)),
                         pk2(fmaxf(c0[2], 0.f), fmaxf(c0[3], 0.f)) };
            u32x2 p1 = { pk2(fmaxf(c1[0], 0.f), fmaxf(c1[1], 0.f)),
                         pk2(fmaxf(c1[2], 0.f), fmaxf(c1[3], 0.f)) };
            __builtin_memcpy(__builtin_assume_aligned(&ks[l16 * KDSTR + di * 16 + quad * 4], 8), &p0, 8);
            __builtin_memcpy(__builtin_assume_aligned(&ks[(16 + l16) * KDSTR + di * 16 + quad * 4], 8), &p1, 8);
        }
        if (k < KK - 1) loadW(obase, k + 1, wB);
        #pragma unroll
        for (int ds = 0; ds < 2; ++ds) {
            bf16x8 kb0 = ld8(&ks[l16 * KDSTR + ds * 32 + quad * 8]);
            bf16x8 kb1 = ld8(&ks[(16 + l16) * KDSTR + ds * 32 + quad * 8]);
            bf16x8 ap0 = ld8(&s_pept[(k + l16) * PSTR + dh * 64 + ds * 32 + quad * 8]);
            bf16x8 ap1 = ld8(&s_pept[(k + 16 + l16) * PSTR + dh * 64 + ds * 32 + quad * 8]);
            acc00 = mfma16(ap0, kb0, acc00);
            acc01 = mfma16(ap0, kb1, acc01);
            acc10 = mfma16(ap1, kb0, acc10);
            acc11 = mfma16(ap1, kb1, acc11);
        }
    }

    if (dh == 1) {
        float* ox = (float*)ks;
        const int fb = lane * 16;
        __builtin_memcpy(__builtin_assume_aligned(&ox[fb +  0], 16), &acc00, 16);
        __builtin_memcpy(__builtin_assume_aligned(&ox[fb +  4], 16), &acc01, 16);
        __builtin_memcpy(__builtin_assume_aligned(&ox[fb +  8], 16), &acc10, 16);
        __builtin_memcpy(__builtin_assume_aligned(&ox[fb + 12], 16), &acc11, 16);
    }
    __syncthreads();
    if (dh == 0) {
        const float* px = (const float*)(s_mem + PEPT_U16 + (wave + 1) * KS_U16);
        const int fb = lane * 16;
        f32x4 q00, q01, q10, q11;
        __builtin_memcpy(&q00, __builtin_assume_aligned(&px[fb +  0], 16), 16);
        __builtin_memcpy(&q01, __builtin_assume_aligned(&px[fb +  4], 16), 16);
        __builtin_memcpy(&q10, __builtin_assume_aligned(&px[fb +  8], 16), 16);
        __builtin_memcpy(&q11, __builtin_assume_aligned(&px[fb + 12], 16), 16);
        const float bv0 = bias[obase + l16];
        const float bv1 = bias[obase + 16 + l16];
        f32x4 r00 = acc00 + q00 + bv0;
        f32x4 r01 = acc01 + q01 + bv1;
        f32x4 r10 = acc10 + q10 + bv0;
        f32x4 r11 = acc11 + q11 + bv1;
        float* ob = out + ((size_t)n * OO + obase) * TT;
        __builtin_memcpy(__builtin_assume_aligned(ob + (size_t)l16 * TT + quad * 4, 16), &r00, 16);
        __builtin_memcpy(__builtin_assume_aligned(ob + (size_t)(16 + l16) * TT + quad * 4, 16), &r01, 16);
        __builtin_memcpy(__builtin_assume_aligned(ob + (size_t)l16 * TT + 16 + quad * 4, 16), &r10, 16);
        __builtin_memcpy(__builtin_assume_aligned(ob + (size_t)(16 + l16) * TT + 16 + quad * 4, 16), &r11, 16);
    }
}

extern "C" void kernel_launch(void* const* d_in, const int* in_sizes, int n_in,
                              void* d_out, int out_size, void* d_ws, size_t ws_size,
                              hipStream_t stream) {
    const float* pept = (const float*)d_in[0];
    const float* mhc  = (const float*)d_in[1];
    const float* wgt  = (const float*)d_in[2];
    const float* bias = (const float*)d_in[3];
    float* out = (float*)d_out;

    const size_t w_bytes = (size_t)OO * KK * WPADL * sizeof(u16);   // 294,912
    const size_t p_bytes = (size_t)NN * LL * DD * sizeof(u16);      // 5,242,880
    if (ws_size >= w_bytes + p_bytes) {
        u16* wp = (u16*)d_ws;
        u16* pp = (u16*)((char*)d_ws + w_bytes);
        const int total = OO * KK * (WPADL / 2) + NN * LL * DD / 2;  // 1,347,584
        cvt_all<<<dim3((total + 255) / 256), dim3(256), 0, stream>>>(wgt, pept, (u32*)wp, (u32*)pp);
        iconv_fast<<<dim3(NN * 4), dim3(256), 0, stream>>>(mhc, wp, pp, bias, out);
    } else {
        iconv_ref<<<dim3(NN * 4), dim3(256), 0, stream>>>(pept, mhc, wgt, bias, out);
    }
}